// Round 11
// baseline (751.056 us; speedup 1.0000x reference)
//
#include <hip/hip_runtime.h>
#include <math.h>

// Problem constants
#define NXg 128
#define NYg 128
#define Pg  (NXg*NYg)      // 16384 pixels
#define Bq  64             // batch
#define Wd  64             // WIDTH (channels)
#define NKX 24             // kept kx rows: 0..11 and 116..127
#define NMODE (NKX*12)     // 288
#define PI2_128 0.04908738521234052f   // 2*pi/128

typedef _Float16 f16x8 __attribute__((ext_vector_type(8)));
typedef _Float16 f16x4 __attribute__((ext_vector_type(4)));
typedef float    f32x4 __attribute__((ext_vector_type(4)));

// ---------------- workspace layout ----------------
// fp32 region (float offsets): just the 128-entry twiddle tables for k_final
#define OFF_TC  0
#define OFF_TS  (OFF_TC + 128)
#define F32_END (OFF_TS + 128)
// fp16 region (half offsets from (W + F32_END)):
#define H_T1E  0                          // T1e  [t=32][y=128]
#define H_T1ET (H_T1E + 32*128)           // T1eT [y=128][t=32]
#define H_A2   (H_T1ET + 128*32)          // A2   [48][256]
#define H_PWH  (H_A2 + 48*256)            // PWh  [4][64][64]
#define H_T2ET (H_PWH + 4*64*64)          // T2eT [x=128][k=64]
#define H_XFHR (H_T2ET + 128*64)          // xfh  [mode=288][bc=4096] fp16
#define H_XFHI (H_XFHR + 288*4096)
#define H_OFHR (H_XFHI + 288*4096)        // ofh  [mode][bc] fp16
#define H_OFHI (H_OFHR + 288*4096)
#define H_WHR  (H_OFHI + 288*4096)        // Wh   [4][288][o=64][i=64] fp16
#define H_WHI  (H_WHR + (size_t)4*288*4096)
#define H_YG   (H_WHI + (size_t)4*288*4096)       // Yg [b*c][x][t=24]
#define H_X    (H_YG + (size_t)Bq*Wd*128*24)      // x  [b][x][y][c]
#define H_U    (H_X + (size_t)Bq*128*128*64)      // val/cnt (8 MB) then Gh

// ---------------- fast gelu: 0.5*v*(1+erf(v/sqrt2)), A&S 7.1.26 erf ----------------
__device__ __forceinline__ float fast_gelu(float v) {
    float a = fabsf(v) * 0.70710678118654752f;
    float t = 1.f / (1.f + 0.3275911f * a);
    float p = t * (0.254829592f + t * (-0.284496736f + t * (1.421413741f +
              t * (-1.453152027f + t * 1.061405429f))));
    float er = 1.f - p * __expf(-a * a);
    er = copysignf(er, v);
    return 0.5f * v * (1.f + er);
}

// ---------------- prep: tables + scatter + coalesced weight transpose ----------------
// grid 368 blocks x 256: blk<64 tables; 64..79 scatter; 80..367 Wh transpose
__global__ void k_prep(_Float16* T1e_g, _Float16* T1eT_g, _Float16* A2_g,
                       const float* pww, _Float16* PWh, _Float16* T2eT_g,
                       float* Tc, float* Ts,
                       const float* xyt, const float* obs_c, const float* obs_v,
                       const int* nb, const int* siy, const int* six,
                       float* val, float* cnt,
                       const float* w1r, const float* w1i,
                       const float* w2r, const float* w2i,
                       _Float16* Whr, _Float16* Whi) {
    int blk = blockIdx.x;
    if (blk < 64) {
        int t = blk * 256 + threadIdx.x;   // 0..16383
        if (t < 32*128) {
            int r = t >> 7, y = t & 127;
            float v = 0.f;
            if (r < 12)      v =  cosf((float)((r * y) & 127) * PI2_128);
            else if (r < 24) v = -sinf((float)(((r-12) * y) & 127) * PI2_128);
            T1e_g[t] = (_Float16)v;
            int y2 = t >> 5, r2 = t & 31;
            float v2 = 0.f;
            if (r2 < 12)      v2 =  cosf((float)((r2 * y2) & 127) * PI2_128);
            else if (r2 < 24) v2 = -sinf((float)(((r2-12) * y2) & 127) * PI2_128);
            T1eT_g[t] = (_Float16)v2;
        }
        if (t < 48*256) {
            int m = t >> 8, k = t & 255;
            int x = k & 127;
            int hi = (k >= 128);
            float v;
            if (m < 24) {
                int kx = (m < 12) ? m : (104 + m);
                float th = (float)((kx * x) & 127) * PI2_128;
                v = hi ? sinf(th) : cosf(th);
            } else {
                int mm = m - 24;
                int kx = (mm < 12) ? mm : (104 + mm);
                float th = (float)((kx * x) & 127) * PI2_128;
                v = hi ? cosf(th) : -sinf(th);
            }
            A2_g[t] = (_Float16)v;
        }
        if (t < 4*64*64) PWh[t] = (_Float16)pww[t];
        if (t < 128*64) {
            int x = t >> 6, k = t & 63;
            float v = 0.f;
            if (k < 24) {
                int kx = (k < 12) ? k : (104 + k);
                v = cosf((float)((kx * x) & 127) * PI2_128);
            } else if (k < 48) {
                int kk = k - 24;
                int kx = (kk < 12) ? kk : (104 + kk);
                v = sinf((float)((kx * x) & 127) * PI2_128);
            }
            T2eT_g[t] = (_Float16)v;
        }
        if (t < 128) {
            float th = (float)t * PI2_128;
            Tc[t] = cosf(th);
            Ts[t] = sinf(th);
        }
    } else if (blk < 80) {
        int t = (blk - 64) * 256 + threadIdx.x;   // 0..4095 = B*K
        int b = t >> 6;
        int id = nb[t];
        int sid = id / 50;                        // NT = 50
        float tq = xyt[b*3 + 2];
        float w = expf(-0.1f * fabsf(obs_c[id*3 + 2] - tq));
        int lin = siy[sid] * NYg + six[sid];
        atomicAdd(&val[b*Pg + lin], obs_v[id] * w);
        atomicAdd(&cnt[b*Pg + lin], w);
    } else {
        // Wh transpose, coalesced reads: u in [0,288): (layer, tensor, 16K-chunk)
        // source layout w[layer][i][o][kx][ky] fp32; dest Wh[layer][mode][o][i] fp16
        int u = blk - 80;
        int lt = u / 36;                 // layer*2 + tensor
        int layer = lt >> 1, tens = lt & 1;
        int cb = u - lt*36;              // chunk 0..35 of 16384 floats
        const float* srcr = (tens ? w2r : w1r) + (size_t)layer*589824 + cb*16384;
        const float* srci = (tens ? w2i : w1i) + (size_t)layer*589824 + cb*16384;
        int mbase = tens ? 144 : 0;      // w2 modes are 144..287
        for (int k = 0; k < 16; k++) {
            int p = k*1024 + threadIdx.x*4;
            float4 vr = *(const float4*)&srcr[p];
            float4 vi = *(const float4*)&srci[p];
            int idx = cb*16384 + p;      // ((i*64+o)*12+kx)*12+ky
            #pragma unroll
            for (int j = 0; j < 4; j++) {
                int id = idx + j;
                int ky = id % 12; int t2 = id / 12;
                int kx = t2 % 12; int t3 = t2 / 12;
                int o = t3 & 63;  int i = t3 >> 6;
                size_t d = ((size_t)(layer*288 + mbase + kx*12 + ky))*4096 + o*64 + i;
                Whr[d] = (_Float16)(&vr.x)[j];
                Whi[d] = (_Float16)(&vi.x)[j];
            }
        }
    }
}

// ---------------- stage-A y-DFT epilogue (shared) ----------------
// Yk[o][t] = sum_y Xn[y][o] * T1e[t][y]; A-frags via scalar column reads of Xn.
__device__ __forceinline__ void stageA(const _Float16 (*Xn)[76], const _Float16* __restrict__ T1e_g,
                                       _Float16* __restrict__ Yg, int b, int row, int tid) {
    int wave = tid >> 6, lane = tid & 63;
    int l15 = lane & 15, quad = lane >> 4;
    f16x8 af[4];
    #pragma unroll
    for (int q = 0; q < 4; q++)
        #pragma unroll
        for (int j = 0; j < 8; j++)
            af[q][j] = Xn[q*32 + quad*8 + j][wave*16 + l15];
    #pragma unroll
    for (int nt2 = 0; nt2 < 2; nt2++) {
        f32x4 acc = {0.f,0.f,0.f,0.f};
        #pragma unroll
        for (int q = 0; q < 4; q++) {
            f16x8 bf = *(const f16x8*)&T1e_g[(nt2*16 + l15)*128 + q*32 + quad*8];
            acc = __builtin_amdgcn_mfma_f32_16x16x32_f16(af[q], bf, acc, 0, 0, 0);
        }
        int t = nt2*16 + l15;
        if (t < 24) {
            #pragma unroll
            for (int r = 0; r < 4; r++) {
                int o = wave*16 + quad*4 + r;
                Yg[((size_t)(b*64 + o)*128 + row)*24 + t] = (_Float16)acc[r];
            }
        }
    }
}

// ---------------- fc0-lite: compute fc0 + stage-A only (no x store) ----------------
__global__ __launch_bounds__(256) void k_fc0y(const float* __restrict__ val, const float* __restrict__ cnt,
                      const float* __restrict__ xg, const float* __restrict__ yg,
                      const float* __restrict__ w, const float* __restrict__ bb,
                      const _Float16* __restrict__ T1e_g,
                      _Float16* __restrict__ Yg) {
    __shared__ _Float16 Xn[128][76];
    __shared__ float wl[4][64];
    int row = blockIdx.x, b = blockIdx.y;
    int tid = threadIdx.x;
    if (tid < 64) {
        wl[0][tid] = w[tid]; wl[1][tid] = w[64+tid]; wl[2][tid] = w[128+tid]; wl[3][tid] = bb[tid];
    }
    __syncthreads();
    {
        int y = tid & 127, half = tid >> 7;
        int p = row*128 + y;
        float c = cnt[(size_t)b*Pg + p];
        float g = (c > 0.f) ? val[(size_t)b*Pg + p] / fmaxf(c, 1e-6f) : 0.f;
        float a1 = xg[p], a2 = yg[p];
        #pragma unroll
        for (int blk = 0; blk < 4; blk++) {
            f16x8 pk;
            #pragma unroll
            for (int j = 0; j < 8; j++) {
                int o = half*32 + blk*8 + j;
                pk[j] = (_Float16)(g*wl[0][o] + a1*wl[1][o] + a2*wl[2][o] + wl[3][o]);
            }
            *(f16x8*)&Xn[y][half*32 + blk*8] = pk;
        }
    }
    __syncthreads();
    stageA(Xn, T1e_g, Yg, b, row, tid);
}

// ---------------- sB: stage-B x-DFT via MFMA; vectorized Yg loads ----------------
__global__ __launch_bounds__(256) void k_sB(const _Float16* __restrict__ Yg,
                    const _Float16* __restrict__ A2_g,
                    _Float16* __restrict__ xfhr, _Float16* __restrict__ xfhi) {
    __shared__ _Float16 Ys[28][136];
    int bc = blockIdx.x;
    int tid = threadIdx.x;
    int wave = tid >> 6, lane = tid & 63;
    int l15 = lane & 15, quad = lane >> 4;
    const _Float16* base = Yg + (size_t)bc * 3072;
    for (int i = tid; i < 384; i += 256) {
        int x = i / 3, seg = i - x*3;
        f16x8 v = *(const f16x8*)&base[x*24 + seg*8];
        #pragma unroll
        for (int j = 0; j < 8; j++) Ys[seg*8 + j][x] = v[j];
    }
    __syncthreads();
    if (wave < 3) {
        f32x4 acc = {0.f,0.f,0.f,0.f};
        #pragma unroll
        for (int q = 0; q < 8; q++) {
            f16x8 a = *(const f16x8*)&A2_g[(size_t)(wave*16 + l15)*256 + q*32 + quad*8];
            const _Float16* brow = (q < 4) ? &Ys[l15][q*32 + quad*8]
                                           : &Ys[12 + l15][(q-4)*32 + quad*8];
            f16x8 bfr = *(const f16x8*)brow;
            acc = __builtin_amdgcn_mfma_f32_16x16x32_f16(a, bfr, acc, 0, 0, 0);
        }
        if (l15 < 12) {
            #pragma unroll
            for (int r = 0; r < 4; r++) {
                int m = wave*16 + quad*4 + r;
                if (m < 24) xfhr[(size_t)(m*12 + l15)*4096 + bc] = (_Float16)acc[r];
                else        xfhi[(size_t)((m-24)*12 + l15)*4096 + bc] = (_Float16)acc[r];
            }
        }
    }
}

// ---------------- s3m: mode mixing via MFMA (all 4 layers) ----------------
__global__ __launch_bounds__(256) void k_s3m(const _Float16* __restrict__ xfhr, const _Float16* __restrict__ xfhi,
                    const _Float16* __restrict__ Whr, const _Float16* __restrict__ Whi,
                    _Float16* __restrict__ ofhr, _Float16* __restrict__ ofhi, int layer) {
    __shared__ _Float16 Xr[64][72], Xi[64][72];
    int mode = blockIdx.x;
    int tid = threadIdx.x;
    int wave = tid >> 6, lane = tid & 63;
    int l15 = lane & 15, quad = lane >> 4;
    const _Float16* pr = xfhr + (size_t)mode * 4096;
    const _Float16* pi = xfhi + (size_t)mode * 4096;
    for (int c8 = tid; c8 < 512; c8 += 256) {
        int b = c8 >> 3, seg = c8 & 7;
        *(f16x8*)&Xr[b][seg*8] = *(const f16x8*)&pr[c8*8];
        *(f16x8*)&Xi[b][seg*8] = *(const f16x8*)&pi[c8*8];
    }
    __syncthreads();
    size_t wb = ((size_t)(layer*288 + mode)*64 + wave*16 + l15) * 64 + quad*8;
    f16x8 wr0 = *(const f16x8*)&Whr[wb];
    f16x8 wr1 = *(const f16x8*)&Whr[wb + 32];
    f16x8 wi0 = *(const f16x8*)&Whi[wb];
    f16x8 wi1 = *(const f16x8*)&Whi[wb + 32];
    #pragma unroll
    for (int mt = 0; mt < 4; mt++) {
        f16x8 xr0 = *(const f16x8*)&Xr[mt*16 + l15][quad*8];
        f16x8 xr1 = *(const f16x8*)&Xr[mt*16 + l15][32 + quad*8];
        f16x8 xi0 = *(const f16x8*)&Xi[mt*16 + l15][quad*8];
        f16x8 xi1 = *(const f16x8*)&Xi[mt*16 + l15][32 + quad*8];
        f16x8 xn0, xn1;
        #pragma unroll
        for (int j = 0; j < 8; j++) { xn0[j] = -xi0[j]; xn1[j] = -xi1[j]; }
        f32x4 cr = {0.f,0.f,0.f,0.f}, ci = {0.f,0.f,0.f,0.f};
        cr = __builtin_amdgcn_mfma_f32_16x16x32_f16(xr0, wr0, cr, 0, 0, 0);
        cr = __builtin_amdgcn_mfma_f32_16x16x32_f16(xr1, wr1, cr, 0, 0, 0);
        cr = __builtin_amdgcn_mfma_f32_16x16x32_f16(xn0, wi0, cr, 0, 0, 0);
        cr = __builtin_amdgcn_mfma_f32_16x16x32_f16(xn1, wi1, cr, 0, 0, 0);
        ci = __builtin_amdgcn_mfma_f32_16x16x32_f16(xr0, wi0, ci, 0, 0, 0);
        ci = __builtin_amdgcn_mfma_f32_16x16x32_f16(xr1, wi1, ci, 0, 0, 0);
        ci = __builtin_amdgcn_mfma_f32_16x16x32_f16(xi0, wr0, ci, 0, 0, 0);
        ci = __builtin_amdgcn_mfma_f32_16x16x32_f16(xi1, wr1, ci, 0, 0, 0);
        #pragma unroll
        for (int r = 0; r < 4; r++) {
            int b = mt*16 + quad*4 + r;
            int o = wave*16 + l15;
            ofhr[(size_t)mode*4096 + b*64 + o] = (_Float16)cr[r];
            ofhi[(size_t)mode*4096 + b*64 + o] = (_Float16)ci[r];
        }
    }
}

// ---------------- sG: inverse-x as MFMA GEMM: Gh[b][t][x][o] ----------------
__global__ __launch_bounds__(256) void k_sG(const _Float16* __restrict__ ofhr, const _Float16* __restrict__ ofhi,
                    const _Float16* __restrict__ T2eT_g, _Float16* __restrict__ Gh) {
    __shared__ _Float16 As[64][72];
    __shared__ _Float16 Cs[128][72];
    int b = blockIdx.x, t = blockIdx.y;
    int tid = threadIdx.x;
    int wave = tid >> 6, lane = tid & 63;
    int l15 = lane & 15, quad = lane >> 4;
    int ky = (t < 12) ? t : (t - 12);
    float sc = ((ky == 0) ? 1.f : 2.f) * (1.f/16384.f);
    bool isReal = (t < 12);
    for (int i = tid; i < 1536; i += 256) {
        int kxi = i >> 6, o = i & 63;
        size_t idx = (size_t)(kxi*12 + ky)*4096 + b*64 + o;
        float vr = (float)ofhr[idx] * sc, vi = (float)ofhi[idx] * sc;
        As[o][kxi]      = (_Float16)(isReal ? vr : vi);
        As[o][24 + kxi] = (_Float16)(isReal ? -vi : vr);
    }
    for (int i = tid; i < 1024; i += 256)
        As[i >> 4][48 + (i & 15)] = (_Float16)0.f;
    __syncthreads();
    f16x8 a0 = *(const f16x8*)&As[wave*16 + l15][quad*8];
    f16x8 a1 = *(const f16x8*)&As[wave*16 + l15][32 + quad*8];
    #pragma unroll
    for (int nt = 0; nt < 8; nt++) {
        f16x8 b0 = *(const f16x8*)&T2eT_g[(nt*16 + l15)*64 + quad*8];
        f16x8 b1 = *(const f16x8*)&T2eT_g[(nt*16 + l15)*64 + 32 + quad*8];
        f32x4 acc = {0.f,0.f,0.f,0.f};
        acc = __builtin_amdgcn_mfma_f32_16x16x32_f16(a0, b0, acc, 0, 0, 0);
        acc = __builtin_amdgcn_mfma_f32_16x16x32_f16(a1, b1, acc, 0, 0, 0);
        f16x4 pk;
        #pragma unroll
        for (int r = 0; r < 4; r++) pk[r] = (_Float16)acc[r];
        *(f16x4*)&Cs[nt*16 + l15][wave*16 + quad*4] = pk;
    }
    __syncthreads();
    _Float16* outp = Gh + ((size_t)(b*24 + t) << 13);
    float4* o4 = (float4*)outp;
    for (int i = tid; i < 1024; i += 256) {
        int x = i >> 3, seg = i & 7;
        o4[i] = *(const float4*)&Cs[x][seg*8];
    }
}

// ---------------- S45: fused [pointwise | inverse-y] MFMA + gelu + y-DFT ----------------
// Register-lean: b2/T1eT loads in-loop; gelu+pack before barrier (f16x4 pk[8] live, not f32x4[8]).
__global__ __launch_bounds__(256, 7) void k_s45(_Float16* __restrict__ xh,
                    const _Float16* __restrict__ Gh,
                    const _Float16* __restrict__ T1e_g, const _Float16* __restrict__ T1eT_g,
                    const _Float16* __restrict__ PWh,
                    const float* __restrict__ pwb,
                    _Float16* __restrict__ Yg, int layer,
                    const float* __restrict__ xyt, const int* __restrict__ Lx,
                    const float* __restrict__ val, const float* __restrict__ cnt,
                    const float* __restrict__ xg, const float* __restrict__ yg,
                    const float* __restrict__ fc0w, const float* __restrict__ fc0b) {
    __shared__ _Float16 BsT[128][76];   // [y][c]; also holds post-gelu output
    __shared__ float wl[4][64];
    int row = blockIdx.x, b = blockIdx.y;
    int tid = threadIdx.x;
    int wave = tid >> 6, lane = tid & 63;
    int l15 = lane & 15, quad = lane >> 4;

    _Float16* xrow = xh + (size_t)(b*128 + row) * 8192;

    // hoisted A-operands only (12 VGPRs) + bias
    f16x8 af0 = *(const f16x8*)&PWh[(size_t)(layer*64 + wave*16 + l15)*64 + quad*8];
    f16x8 af1 = *(const f16x8*)&PWh[(size_t)(layer*64 + wave*16 + l15)*64 + 32 + quad*8];
    f16x8 af2;
    #pragma unroll
    for (int j = 0; j < 8; j++) af2[j] = (_Float16)0.f;
    if (quad < 3) {
        const _Float16* gbase = Gh + ((size_t)(b*24 + quad*8)*128 + row)*64 + wave*16 + l15;
        #pragma unroll
        for (int j = 0; j < 8; j++) af2[j] = gbase[(size_t)j * 8192];
    }
    float pb[4];
    #pragma unroll
    for (int r = 0; r < 4; r++)
        pb[r] = pwb[layer*64 + wave*16 + quad*4 + r];

    // x tile fill: layer 0 recomputes fc0; others load from xh
    if (layer == 0) {
        if (tid < 64) {
            wl[0][tid] = fc0w[tid]; wl[1][tid] = fc0w[64+tid];
            wl[2][tid] = fc0w[128+tid]; wl[3][tid] = fc0b[tid];
        }
        __syncthreads();
        int y = tid & 127, half = tid >> 7;
        int p = row*128 + y;
        float c = cnt[(size_t)b*Pg + p];
        float g = (c > 0.f) ? val[(size_t)b*Pg + p] / fmaxf(c, 1e-6f) : 0.f;
        float a1 = xg[p], a2 = yg[p];
        #pragma unroll
        for (int blk = 0; blk < 4; blk++) {
            f16x8 pk;
            #pragma unroll
            for (int j = 0; j < 8; j++) {
                int o = half*32 + blk*8 + j;
                pk[j] = (_Float16)(g*wl[0][o] + a1*wl[1][o] + a2*wl[2][o] + wl[3][o]);
            }
            *(f16x8*)&BsT[y][half*32 + blk*8] = pk;
        }
    } else {
        const float4* xr4 = (const float4*)xrow;
        for (int i = tid; i < 1024; i += 256) {
            int y = i >> 3, seg = i & 7;
            *(float4*)&BsT[y][seg*8] = xr4[i];
        }
    }
    __syncthreads();

    // main GEMM + gelu + pack (pre-barrier): pk[8] = 16 VGPRs live
    f16x4 pk[8];
    #pragma unroll
    for (int nt = 0; nt < 8; nt++) {
        f16x8 b0 = *(const f16x8*)&BsT[nt*16 + l15][quad*8];
        f16x8 b1 = *(const f16x8*)&BsT[nt*16 + l15][32 + quad*8];
        f16x8 b2 = *(const f16x8*)&T1eT_g[(nt*16 + l15)*32 + quad*8];
        f32x4 a = {0.f,0.f,0.f,0.f};
        a = __builtin_amdgcn_mfma_f32_16x16x32_f16(af0, b0, a, 0, 0, 0);
        a = __builtin_amdgcn_mfma_f32_16x16x32_f16(af1, b1, a, 0, 0, 0);
        a = __builtin_amdgcn_mfma_f32_16x16x32_f16(af2, b2, a, 0, 0, 0);
        #pragma unroll
        for (int r = 0; r < 4; r++)
            pk[nt][r] = (_Float16)fast_gelu(a[r] + pb[r]);
    }
    __syncthreads();   // all BsT reads complete before overwrite

    #pragma unroll
    for (int nt = 0; nt < 8; nt++)
        *(f16x4*)&BsT[nt*16 + l15][wave*16 + quad*4] = pk[nt];
    __syncthreads();

    // x store (layer 2: only the two rows k_final will read)
    bool store_x = true;
    if (layer == 2) {
        float Lxf = fmaxf((float)Lx[0], 1e-6f);
        float x01 = fminf(fmaxf(xyt[b*3 + 0] / Lxf, 0.f), 1.f);
        float gxp = x01 * (NXg - 1);
        int x0 = (int)floorf(gxp);
        int x1 = min(x0 + 1, NXg - 1);
        store_x = (row == x0) || (row == x1);
    }
    if (store_x) {
        float4* xw4 = (float4*)xrow;
        for (int i = tid; i < 1024; i += 256) {
            int y = i >> 3, seg = i & 7;
            xw4[i] = *(const float4*)&BsT[y][seg*8];
        }
    }
    stageA(BsT, T1e_g, Yg, b, row, tid);
}

// ---------------- final: layer-3 at 4 points + fc1 + fc2 + bilinear ----------------
__global__ __launch_bounds__(256) void k_final(const _Float16* __restrict__ x,
                    const _Float16* __restrict__ ofhr, const _Float16* __restrict__ ofhi,
                    const float* __restrict__ pw, const float* __restrict__ pwb,
                    const float* __restrict__ fc1w, const float* __restrict__ fc1b,
                    const float* __restrict__ fc2w, const float* __restrict__ fc2b,
                    const float* __restrict__ xyt, const int* __restrict__ Lx, const int* __restrict__ Ly,
                    const float* __restrict__ Tc, const float* __restrict__ Ts,
                    float* __restrict__ out) {
    __shared__ float y4[4][64];
    __shared__ float hh[4][129];
    __shared__ int   pxy[4][2];
    __shared__ float wxy[2];
    __shared__ float tc[128], ts[128];
    int b = blockIdx.x;
    if (threadIdx.x < 128) {
        tc[threadIdx.x] = Tc[threadIdx.x];
        ts[threadIdx.x] = Ts[threadIdx.x];
    }
    if (threadIdx.x == 0) {
        float Lxf = fmaxf((float)Lx[0], 1e-6f);
        float Lyf = fmaxf((float)Ly[0], 1e-6f);
        float x01 = fminf(fmaxf(xyt[b*3 + 0] / Lxf, 0.f), 1.f);
        float y01 = fminf(fmaxf(xyt[b*3 + 1] / Lyf, 0.f), 1.f);
        float gx = x01 * (NXg - 1), gy = y01 * (NYg - 1);
        int x0 = (int)floorf(gx), y0 = (int)floorf(gy);
        int x1 = min(x0 + 1, NXg - 1), y1 = min(y0 + 1, NYg - 1);
        wxy[0] = gx - (float)x0;
        wxy[1] = gy - (float)y0;
        pxy[0][0] = x0; pxy[0][1] = y0;
        pxy[1][0] = x1; pxy[1][1] = y0;
        pxy[2][0] = x0; pxy[2][1] = y1;
        pxy[3][0] = x1; pxy[3][1] = y1;
    }
    __syncthreads();
    {
        int p = threadIdx.x >> 6, o = threadIdx.x & 63;
        int px = pxy[p][0], py = pxy[p][1];
        float gkr[12], gki[12];
        #pragma unroll
        for (int ky = 0; ky < 12; ky++) { gkr[ky] = 0.f; gki[ky] = 0.f; }
        for (int kxi = 0; kxi < 24; kxi++) {
            int kx = (kxi < 12) ? kxi : (104 + kxi);
            int m = (kx * px) & 127;
            float cc = tc[m], ss = ts[m];
            #pragma unroll
            for (int ky = 0; ky < 12; ky++) {
                size_t idx = (size_t)(kxi*12 + ky)*4096 + b*64 + o;
                float a = (float)ofhr[idx], bb = (float)ofhi[idx];
                gkr[ky] += a*cc - bb*ss;
                gki[ky] += a*ss + bb*cc;
            }
        }
        float sp = gkr[0];
        #pragma unroll
        for (int ky = 1; ky < 12; ky++) {
            int m = (ky * py) & 127;
            sp += 2.f * (gkr[ky]*tc[m] - gki[ky]*ts[m]);
        }
        float s = 0.f;
        const _Float16* xb = x + ((size_t)(b*128 + px)*128 + py)*64;
        #pragma unroll 4
        for (int c = 0; c < 64; c++)
            s += pw[3*4096 + o*64 + c] * (float)xb[c];
        y4[p][o] = sp * (1.f/16384.f) + s + pwb[3*64 + o];
    }
    __syncthreads();
    for (int i = threadIdx.x; i < 512; i += 256) {
        int p = i >> 7, f = i & 127;
        float s = fc1b[f];
        #pragma unroll 4
        for (int w = 0; w < 64; w++) s += y4[p][w] * fc1w[w*128 + f];
        hh[p][f] = 0.5f * s * (1.f + erff(s * 0.70710678118654752f));
    }
    __syncthreads();
    if (threadIdx.x < 3) {
        int o3 = threadIdx.x;
        float f4[4];
        #pragma unroll
        for (int p = 0; p < 4; p++) {
            float s = fc2b[o3];
            #pragma unroll 4
            for (int f = 0; f < 128; f++) s += hh[p][f] * fc2w[f*3 + o3];
            f4[p] = s;
        }
        float wx = wxy[0], wy = wxy[1];
        float top = f4[0]*(1.f - wx) + f4[1]*wx;
        float bot = f4[2]*(1.f - wx) + f4[3]*wx;
        out[b*3 + o3] = top*(1.f - wy) + bot*wy;
    }
}

extern "C" void kernel_launch(void* const* d_in, const int* in_sizes, int n_in,
                              void* d_out, int out_size, void* d_ws, size_t ws_size,
                              hipStream_t stream) {
    const float* xyt    = (const float*)d_in[0];
    const float* obs_c  = (const float*)d_in[1];
    const float* obs_v  = (const float*)d_in[2];
    const float* xg     = (const float*)d_in[3];
    const float* yg     = (const float*)d_in[4];
    const float* fc0w   = (const float*)d_in[5];
    const float* fc0b   = (const float*)d_in[6];
    const float* w1r    = (const float*)d_in[7];
    const float* w1i    = (const float*)d_in[8];
    const float* w2r    = (const float*)d_in[9];
    const float* w2i    = (const float*)d_in[10];
    const float* pww    = (const float*)d_in[11];
    const float* pwb    = (const float*)d_in[12];
    const float* fc1w   = (const float*)d_in[13];
    const float* fc1b   = (const float*)d_in[14];
    const float* fc2w   = (const float*)d_in[15];
    const float* fc2b   = (const float*)d_in[16];
    const int*   nb     = (const int*)d_in[17];
    const int*   siy    = (const int*)d_in[18];
    const int*   six    = (const int*)d_in[19];
    const int*   Lx     = (const int*)d_in[20];
    const int*   Ly     = (const int*)d_in[21];
    float* out = (float*)d_out;

    float* W = (float*)d_ws;
    float* Tc  = W + OFF_TC;
    float* Ts  = W + OFF_TS;
    _Float16* Hbase = (_Float16*)(W + F32_END);
    _Float16* T1e_g  = Hbase + H_T1E;
    _Float16* T1eT_g = Hbase + H_T1ET;
    _Float16* A2_g   = Hbase + H_A2;
    _Float16* PWh    = Hbase + H_PWH;
    _Float16* T2eT_g = Hbase + H_T2ET;
    _Float16* xfhr   = Hbase + H_XFHR;
    _Float16* xfhi   = Hbase + H_XFHI;
    _Float16* ofhr   = Hbase + H_OFHR;
    _Float16* ofhi   = Hbase + H_OFHI;
    _Float16* Whr    = Hbase + H_WHR;
    _Float16* Whi    = Hbase + H_WHI;
    _Float16* Yg     = Hbase + H_YG;
    _Float16* xh     = Hbase + H_X;
    float*    val    = (float*)(Hbase + H_U);
    float*    cnt    = val + Bq*Pg;
    _Float16* Gh2    = Hbase + H_U + (size_t)4*Bq*Pg;   // after val/cnt (both live in s45 l0)

    hipMemsetAsync(val, 0, (size_t)2 * Bq * Pg * sizeof(float), stream);

    k_prep<<<368, 256, 0, stream>>>(T1e_g, T1eT_g, A2_g, pww, PWh, T2eT_g, Tc, Ts,
                                    xyt, obs_c, obs_v, nb, siy, six, val, cnt,
                                    w1r, w1i, w2r, w2i, Whr, Whi);
    k_fc0y<<<dim3(128, Bq), 256, 0, stream>>>(val, cnt, xg, yg, fc0w, fc0b, T1e_g, Yg);

    for (int l = 0; l < 3; l++) {
        k_sB<<<Bq*Wd, 256, 0, stream>>>(Yg, A2_g, xfhr, xfhi);
        k_s3m<<<288, 256, 0, stream>>>(xfhr, xfhi, Whr, Whi, ofhr, ofhi, l);
        k_sG<<<dim3(Bq, 24), 256, 0, stream>>>(ofhr, ofhi, T2eT_g, Gh2);
        k_s45<<<dim3(128, Bq), 256, 0, stream>>>(xh, Gh2, T1e_g, T1eT_g, PWh, pwb, Yg, l,
                                                 xyt, Lx, val, cnt, xg, yg, fc0w, fc0b);
    }
    // layer 3: spectral coefficients (MFMA path) + k_final
    k_sB<<<Bq*Wd, 256, 0, stream>>>(Yg, A2_g, xfhr, xfhi);
    k_s3m<<<288, 256, 0, stream>>>(xfhr, xfhi, Whr, Whi, ofhr, ofhi, 3);
    k_final<<<Bq, 256, 0, stream>>>(xh, ofhr, ofhi, pww, pwb, fc1w, fc1b, fc2w, fc2b,
                                    xyt, Lx, Ly, Tc, Ts, out);
}